// Round 7
// baseline (1818.762 us; speedup 1.0000x reference)
//
#include <hip/hip_runtime.h>
#include <cstdint>
#include <cstddef>

// BiLSTM-CRF forward, MI355X fp32 implementation.
// Pipeline: prep -> proj1(emb gather GEMM) -> lstm1(512 chains) -> proj2(GEMM)
//           -> lstm2(64 chains) -> emission -> viterbi(+backtrace).
// Only valid (packed) tokens are computed; tail tokens provably can't
// affect outputs (mask freezes LSTM2 state and Viterbi score/backtrace).
//
// R7: single-barrier step, conflict-free edition. R6's regression was
// 2.18M LDS bank conflicts from split-block psum reads. Now each wave
// REPLICATES gate computation for its own 32-row h-slice:
//   - psum read = 4 plain b128 reads, stride-1 per half-wave, lanes L/L+32
//     identical (broadcast pair) -> measured-free patterns only.
//   - h_stage is wave-private (write own slice, broadcast-read own slice)
//     -> intra-wave lgkm ordering, no second barrier.
//   - psum parity-double-buffered -> WAR safe with one barrier/step.
// launch_bounds(512,1): R4's (512,2) capped VGPR at 128 and spilled the
// pinned weights. xc/xn double-buffer hides group-prologue load latency.

#define B_    32
#define NSEG_ 8
#define S_    128
#define T_    1024
#define E_    256
#define HD_   128
#define G_    512   // 4*HD
#define K_    16
#define KS_   8     // steps per group (global-traffic amortization)

#define PIN4(v) asm volatile("" : "+v"((v).x), "+v"((v).y), "+v"((v).z), "+v"((v).w))

// ---------------- prep: seg offsets, fused bias, transposed+permuted Wih ----------------
// WT1 column jcol (0..1023): dir=jcol>>9, w=jcol&511, j=w>>2, g=w&3 -> gate row r=g*128+j
// so xproj[p][dir*512 + j*4 .. +4] = (i,f,g,o) gates of hidden j (one float4).
__global__ void prep_kernel(const int* __restrict__ lengths,
                            int* __restrict__ seg_off, int* __restrict__ new_len,
                            const float* __restrict__ bih_f, const float* __restrict__ bhh_f,
                            const float* __restrict__ bih_b, const float* __restrict__ bhh_b,
                            float* __restrict__ bias1,
                            const float* __restrict__ Wih_f, const float* __restrict__ Wih_b,
                            float* __restrict__ WT1)
{
    int gtid = blockIdx.x * blockDim.x + threadIdx.x;
    if (gtid < B_) {
        int acc = 0;
        for (int s = 0; s < NSEG_; s++) { seg_off[gtid*NSEG_ + s] = acc; acc += lengths[gtid*NSEG_ + s]; }
        new_len[gtid] = acc;
    }
    if (gtid < 1024) {
        int dir = gtid >> 9, w = gtid & 511, j = w >> 2, g = w & 3;
        int r = g * HD_ + j;
        bias1[gtid] = dir ? (bih_b[r] + bhh_b[r]) : (bih_f[r] + bhh_f[r]);
    }
    for (int e = gtid; e < 256*1024; e += gridDim.x * blockDim.x) {
        int k = e >> 10, jcol = e & 1023;
        int dir = jcol >> 9, w = jcol & 511, j = w >> 2, g = w & 3;
        int r = g * HD_ + j;
        WT1[e] = dir ? Wih_b[(size_t)r*E_ + k] : Wih_f[(size_t)r*E_ + k];
    }
}

// ---------------- projection GEMM: xproj[b][p][j] = A[p][:] . WT1[:][j] + bias1[j] ----------------
// MODE 0: A row = emb_table[texts[...]] (gather); MODE 1: A row = lstm_packed[b][p][:]
template <int MODE>
__global__ void __launch_bounds__(256, 4)
proj_kernel(const int* __restrict__ texts, const float* __restrict__ emb,
            const float* __restrict__ WT1, const float* __restrict__ bias1,
            const float* __restrict__ lstm_packed, float* __restrict__ xproj,
            const int* __restrict__ seg_off, const int* __restrict__ new_len)
{
    int b  = blockIdx.z;
    int nl = new_len[b];
    int p0 = blockIdx.x * 32;
    if (p0 >= nl) return;
    int j0 = blockIdx.y * 256;

    __shared__ __align__(16) float As[32][256];
    __shared__ const float* rowp[32];
    int tid = threadIdx.x;
    if (tid < 32) {
        int p = p0 + tid;
        const float* r = emb;  // dummy row for invalid p
        if (p < nl) {
            if (MODE == 0) {
                int sg = 0;
                #pragma unroll
                for (int q = 1; q < NSEG_; q++) if (seg_off[b*NSEG_ + q] <= p) sg = q;
                int t   = p - seg_off[b*NSEG_ + sg];
                int tok = texts[(b*NSEG_ + sg)*S_ + t];
                r = emb + (size_t)tok * E_;
            } else {
                r = lstm_packed + ((size_t)b*T_ + p) * 256;
            }
        }
        rowp[tid] = r;
    }
    __syncthreads();
    #pragma unroll 4
    for (int i = 0; i < 32; i++) As[i][tid] = rowp[i][tid];
    __syncthreads();

    int pg = tid >> 6;        // 0..3 -> rows pg*8 .. pg*8+7
    int jg = tid & 63;        // cols j0 + jg*4 .. +3
    int j  = j0 + jg*4;
    float acc[8][4];
    #pragma unroll
    for (int i = 0; i < 8; i++) { acc[i][0]=0.f; acc[i][1]=0.f; acc[i][2]=0.f; acc[i][3]=0.f; }

    const float* wbase = WT1 + j;
    for (int k = 0; k < 256; k += 4) {
        float4 w0 = *(const float4*)(wbase + (size_t)(k+0)*1024);
        float4 w1 = *(const float4*)(wbase + (size_t)(k+1)*1024);
        float4 w2 = *(const float4*)(wbase + (size_t)(k+2)*1024);
        float4 w3 = *(const float4*)(wbase + (size_t)(k+3)*1024);
        #pragma unroll
        for (int i = 0; i < 8; i++) {
            float4 a = *(const float4*)&As[pg*8 + i][k];
            acc[i][0] = fmaf(a.w, w3.x, fmaf(a.z, w2.x, fmaf(a.y, w1.x, fmaf(a.x, w0.x, acc[i][0]))));
            acc[i][1] = fmaf(a.w, w3.y, fmaf(a.z, w2.y, fmaf(a.y, w1.y, fmaf(a.x, w0.y, acc[i][1]))));
            acc[i][2] = fmaf(a.w, w3.z, fmaf(a.z, w2.z, fmaf(a.y, w1.z, fmaf(a.x, w0.z, acc[i][2]))));
            acc[i][3] = fmaf(a.w, w3.w, fmaf(a.z, w2.w, fmaf(a.y, w1.w, fmaf(a.x, w0.w, acc[i][3]))));
        }
    }
    float4 bs = *(const float4*)(bias1 + j);
    #pragma unroll
    for (int i = 0; i < 8; i++) {
        int p = p0 + pg*8 + i;
        if (p < nl) {
            float4 r;
            r.x = acc[i][0] + bs.x; r.y = acc[i][1] + bs.y;
            r.z = acc[i][2] + bs.z; r.w = acc[i][3] + bs.w;
            *(float4*)(xproj + (((size_t)b*T_ + p) << 10) + j) = r;
        }
    }
}

// ---------------- LSTM chain v7: single barrier, replicated gates ----------------
__device__ __forceinline__ float sig_f(float x) { return 1.0f / (1.0f + __expf(-x)); }
__device__ __forceinline__ float tanh_f(float x) {
    float xc = fminf(fmaxf(x, -15.0f), 15.0f);
    float e  = __expf(-2.0f * xc);
    return (1.0f - e) / (1.0f + e);
}

__device__ __forceinline__ void lstm_chain(
    const float* __restrict__ Whh,     // [512][128] row-major, this dir
    const float* __restrict__ xp,      // xproj for this b: [1024][1024] gate-interleaved
    float* __restrict__ outp,          // lstm_packed for this b: [1024][256]
    int p_base, int len, int dir, int rev,
    const float* __restrict__ h0, const float* __restrict__ c0,
    float* __restrict__ hT, float* __restrict__ cT)
{
    __shared__ __align__(16) float  h_stage[8*32];     // wave-private h slices (1 KB)
    __shared__ __align__(16) float4 psum[2*4*HD_];     // parity x [q'][row] (16 KB)

    int t = threadIdx.x;          // 0..511
    int w = t >> 6, L = t & 63;   // wave, lane
    int q = w >> 1;               // k-slice this wave consumes AND finalizes
    int jF = t & 127;             // psum-production row
    int r  = 32*q + (L & 31);     // gate row this thread finalizes (x2 replicated)
    bool storer = ((w & 1) == 0) && (L < 32);   // unique owner of row r

    // Weights: gate rows jF+128g, k in [32q, 32q+32). Pinned.
    float4 wgt[4][8];
    #pragma unroll
    for (int g = 0; g < 4; g++) {
        const float4* wr = (const float4*)(Whh + (size_t)(jF + 128*g) * HD_ + 32*q);
        #pragma unroll
        for (int i = 0; i < 8; i++) { wgt[g][i] = wr[i]; PIN4(wgt[g][i]); }
    }

    float c_reg = c0 ? c0[r] : 0.0f;
    if (L < 32) h_stage[32*w + L] = h0 ? h0[32*q + L] : 0.0f;   // r == 32q+L here
    __syncthreads();

    const float* xb = xp + dir * G_ + 4 * r;       // float4 col of row r; + (p<<10)
    float*       ob = outp + dir * HD_ + r;        // + p*256 (storer lanes)

    float4 xc[KS_], xn[KS_];
    float  hbuf[KS_];

    // prefetch group 0 (all threads; lanes L/L+32 redundant -> L2 absorbs)
    #pragma unroll
    for (int u = 0; u < KS_; u++) {
        int s = u < len ? u : (len - 1);
        int p = p_base + (rev ? (len - 1 - s) : s);
        xn[u] = *(const float4*)(xb + ((size_t)p << 10));
    }

    for (int gs = 0; gs < len; gs += KS_) {
        // ---- group prologue: flush prev hn, rotate xv, prefetch next group ----
        if (storer && gs > 0) {
            #pragma unroll
            for (int u = 0; u < KS_; u++) {
                int s = gs - KS_ + u;
                int p = p_base + (rev ? (len - 1 - s) : s);
                ob[(size_t)p * 256] = hbuf[u];
            }
        }
        #pragma unroll
        for (int u = 0; u < KS_; u++) xc[u] = xn[u];
        if (gs + KS_ < len) {
            #pragma unroll
            for (int u = 0; u < KS_; u++) {
                int s = gs + KS_ + u; s = s < len ? s : (len - 1);
                int p = p_base + (rev ? (len - 1 - s) : s);
                xn[u] = *(const float4*)(xb + ((size_t)p << 10));
            }
        }
        // ---- KS_ steps, ONE barrier each ----
        #pragma unroll
        for (int u = 0; u < KS_; u++) {
            int sstep = gs + u;
            if (sstep < len) {                     // block-uniform predicate
                int par = (sstep & 1) << 9;        // parity offset in float4 units
                // matvec partials over own k-slice (h from wave-private stage)
                const float4* hv = (const float4*)(h_stage + 32*w);
                float4 a0 = make_float4(0.f,0.f,0.f,0.f);
                float4 a1 = a0, a2 = a0, a3 = a0;
                #pragma unroll
                for (int i = 0; i < 8; i++) {
                    float4 h4 = hv[i];             // broadcast read
                    a0.x = fmaf(h4.x, wgt[0][i].x, a0.x); a0.y = fmaf(h4.y, wgt[0][i].y, a0.y);
                    a0.z = fmaf(h4.z, wgt[0][i].z, a0.z); a0.w = fmaf(h4.w, wgt[0][i].w, a0.w);
                    a1.x = fmaf(h4.x, wgt[1][i].x, a1.x); a1.y = fmaf(h4.y, wgt[1][i].y, a1.y);
                    a1.z = fmaf(h4.z, wgt[1][i].z, a1.z); a1.w = fmaf(h4.w, wgt[1][i].w, a1.w);
                    a2.x = fmaf(h4.x, wgt[2][i].x, a2.x); a2.y = fmaf(h4.y, wgt[2][i].y, a2.y);
                    a2.z = fmaf(h4.z, wgt[2][i].z, a2.z); a2.w = fmaf(h4.w, wgt[2][i].w, a2.w);
                    a3.x = fmaf(h4.x, wgt[3][i].x, a3.x); a3.y = fmaf(h4.y, wgt[3][i].y, a3.y);
                    a3.z = fmaf(h4.z, wgt[3][i].z, a3.z); a3.w = fmaf(h4.w, wgt[3][i].w, a3.w);
                }
                // stride-1 write: wave w covers 1KB contiguous
                psum[par + q*HD_ + jF] = make_float4((a0.x+a0.y)+(a0.z+a0.w),
                                                     (a1.x+a1.y)+(a1.z+a1.w),
                                                     (a2.x+a2.y)+(a2.z+a2.w),
                                                     (a3.x+a3.y)+(a3.z+a3.w));
                __syncthreads();
                // replicated gates: 4 stride-1 b128 reads (halves broadcast-paired)
                float4 s0 = psum[par + 0*HD_ + r];
                float4 s1 = psum[par + 1*HD_ + r];
                float4 s2 = psum[par + 2*HD_ + r];
                float4 s3 = psum[par + 3*HD_ + r];
                float gi = xc[u].x + ((s0.x + s1.x) + (s2.x + s3.x));
                float gf = xc[u].y + ((s0.y + s1.y) + (s2.y + s3.y));
                float gg = xc[u].z + ((s0.z + s1.z) + (s2.z + s3.z));
                float go = xc[u].w + ((s0.w + s1.w) + (s2.w + s3.w));
                float cn = sig_f(gf) * c_reg + sig_f(gi) * tanh_f(gg);
                c_reg = cn;
                float hn = sig_f(go) * tanh_f(cn);
                if (L < 32) h_stage[32*w + L] = hn;     // own slice; lgkm-ordered
                hbuf[u] = hn;
                if (sstep == len - 1 && hT != nullptr && storer) {
                    hT[r] = hn; cT[r] = c_reg;
                }
            }
        }
    }
    // flush last (possibly partial) group
    if (storer && len > 0) {
        int gs0 = ((len - 1) / KS_) * KS_;
        #pragma unroll
        for (int u = 0; u < KS_; u++) {
            int s = gs0 + u;
            if (s < len) {
                int p = p_base + (rev ? (len - 1 - s) : s);
                ob[(size_t)p * 256] = hbuf[u];
            }
        }
    }
}

__global__ void __launch_bounds__(512, 1)
lstm1_kernel(const int* __restrict__ lengths, const int* __restrict__ seg_off,
             const float* __restrict__ Whh_f, const float* __restrict__ Whh_b,
             const float* __restrict__ xproj, float* __restrict__ lstm_packed,
             float* __restrict__ hinit, float* __restrict__ cinit)
{
    int cid = blockIdx.x;                 // 512 = 32b * 8seg * 2dir
    int b = cid >> 4, seg = (cid >> 1) & 7, dir = cid & 1;
    int len = lengths[b*NSEG_ + seg];
    int pb  = seg_off[b*NSEG_ + seg];
    const float* Whh = dir ? Whh_b : Whh_f;
    float* hT = nullptr; float* cT = nullptr;
    if (seg == NSEG_ - 1) {               // final states feed LSTM2 init
        hT = hinit + (dir*B_ + b)*HD_;
        cT = cinit + (dir*B_ + b)*HD_;
    }
    lstm_chain(Whh, xproj + ((size_t)b << 20), lstm_packed + (size_t)b*T_*256,
               pb, len, dir, dir, nullptr, nullptr, hT, cT);
}

__global__ void __launch_bounds__(512, 1)
lstm2_kernel(const int* __restrict__ new_len,
             const float* __restrict__ Whh_f, const float* __restrict__ Whh_b,
             const float* __restrict__ xproj, float* __restrict__ lstm_packed,
             const float* __restrict__ hinit, const float* __restrict__ cinit)
{
    int cid = blockIdx.x;                 // 64 = 32b * 2dir
    int b = cid >> 1, dir = cid & 1;
    int len = new_len[b];
    const float* Whh = dir ? Whh_b : Whh_f;
    lstm_chain(Whh, xproj + ((size_t)b << 20), lstm_packed + (size_t)b*T_*256,
               0, len, dir, dir,
               hinit + (dir*B_ + b)*HD_, cinit + (dir*B_ + b)*HD_,
               nullptr, nullptr);
}

// ---------------- emission: em[b][p][s] = lstm2[b][p][:] . Wlin[s][:] + blin[s] ----------------
__global__ void __launch_bounds__(256)
emission_kernel(const float* __restrict__ lstm_packed, const float* __restrict__ Wlin,
                const float* __restrict__ blin, float* __restrict__ emis,
                const int* __restrict__ new_len)
{
    int b  = blockIdx.y;
    int nl = new_len[b];
    int p0 = blockIdx.x * 16;
    if (p0 >= nl) return;
    int pl = threadIdx.x >> 4, s = threadIdx.x & 15;
    int p  = p0 + pl;
    const float4* xr = (const float4*)(lstm_packed + ((size_t)b*T_ + p) * 256);
    const float4* wr = (const float4*)(Wlin + (size_t)s * 256);
    float ax = 0.f, ay = 0.f, az = 0.f, aw = 0.f;
    #pragma unroll
    for (int i = 0; i < 64; i++) {
        float4 a = xr[i]; float4 ww = wr[i];
        ax = fmaf(a.x, ww.x, ax); ay = fmaf(a.y, ww.y, ay);
        az = fmaf(a.z, ww.z, az); aw = fmaf(a.w, ww.w, aw);
    }
    if (p < nl) emis[((size_t)b*T_ + p)*K_ + s] = (ax + ay) + (az + aw) + blin[s];
}

// ---------------- Viterbi: one block (1 wave) per batch element ----------------
__global__ void __launch_bounds__(64)
viterbi_kernel(const float* __restrict__ emis, const float* __restrict__ start,
               const float* __restrict__ trans, const float* __restrict__ endv,
               const int* __restrict__ new_len, float* __restrict__ out)
{
    int b    = blockIdx.x;
    int nl   = new_len[b];
    int lane = threadIdx.x;          // 64 lanes: 4 q-groups x 16 states
    int s    = lane & 15, q4 = lane >> 4;

    __shared__ unsigned char hist[T_ * K_];   // 16 KB
    __shared__ unsigned char tagb[T_];

    float tr[4];
    #pragma unroll
    for (int jj = 0; jj < 4; jj++) tr[jj] = trans[(q4*4 + jj)*K_ + s];

    const float* em = emis + (size_t)b * T_ * K_;
    float sc = start[s] + em[s];     // p = 0 (always valid)

    for (int p = 1; p < nl; p++) {
        float e = em[p*K_ + s];
        float m = -3.4e38f; int a = 0;
        #pragma unroll
        for (int jj = 0; jj < 4; jj++) {
            int q   = q4*4 + jj;
            float sq = __shfl(sc, q, 16);
            float v  = sq + tr[jj];
            if (v > m) { m = v; a = q; }
        }
        #pragma unroll
        for (int d = 16; d < 64; d <<= 1) {
            float mo = __shfl_xor(m, d);
            int   ao = __shfl_xor(a, d);
            if (mo > m || (mo == m && ao < a)) { m = mo; a = ao; }
        }
        sc = m + e;
        if (lane < K_) hist[p*K_ + s] = (unsigned char)a;
    }

    // final = sc + end; best/argmax (first index on ties)
    float m = sc + endv[s]; int a = s;
    #pragma unroll
    for (int d = 1; d < 16; d <<= 1) {
        float mo = __shfl_xor(m, d);
        int   ao = __shfl_xor(a, d);
        if (mo > m || (mo == m && ao < a)) { m = mo; a = ao; }
    }
    int last = a;
    if (lane == 0) out[T_*B_ + b] = m;
    __syncthreads();

    for (int i = lane; i < T_; i += 64) tagb[i] = (unsigned char)last;
    __syncthreads();
    if (lane == 0) {
        int cur = last;
        for (int j = nl - 2; j >= 0; j--) {
            cur = hist[(j+1)*K_ + cur];
            tagb[j] = (unsigned char)cur;
        }
    }
    __syncthreads();
    for (int i = lane; i < T_; i += 64) out[(size_t)i*B_ + b] = (float)tagb[i];
}

// ---------------- host ----------------
extern "C" void kernel_launch(void* const* d_in, const int* in_sizes, int n_in,
                              void* d_out, int out_size, void* d_ws, size_t ws_size,
                              hipStream_t stream)
{
    (void)in_sizes; (void)n_in; (void)out_size; (void)ws_size;
    const int*   texts   = (const int*)  d_in[0];
    const int*   lengths = (const int*)  d_in[1];
    const float* emb     = (const float*)d_in[2];
    const float* Wih_f   = (const float*)d_in[3];
    const float* Whh_f   = (const float*)d_in[4];
    const float* bih_f   = (const float*)d_in[5];
    const float* bhh_f   = (const float*)d_in[6];
    const float* Wih_b   = (const float*)d_in[7];
    const float* Whh_b   = (const float*)d_in[8];
    const float* bih_b   = (const float*)d_in[9];
    const float* bhh_b   = (const float*)d_in[10];
    const float* Wlin    = (const float*)d_in[11];
    const float* blin    = (const float*)d_in[12];
    const float* c_start = (const float*)d_in[13];
    const float* c_trans = (const float*)d_in[14];
    const float* c_end   = (const float*)d_in[15];
    float* out = (float*)d_out;

    // workspace carve (~163 MB total, all 16B-aligned)
    char* w = (char*)d_ws;
    int*   seg_off     = (int*)(w);                      // 256 ints
    int*   new_len     = (int*)(w + 1024);               // 32 ints
    float* bias1       = (float*)(w + 4096);             // 1024 f
    float* WT1         = (float*)(w + 8192);             // 262144 f (1 MB)
    float* hinit       = (float*)(w + 8192 + 1048576);   // 8192 f
    float* cinit       = hinit + 8192;                   // 8192 f
    float* lstm_packed = cinit + 8192;                   // 32*1024*256 f (32 MB)
    float* xproj       = lstm_packed + (size_t)B_*T_*256;    // 32*1024*1024 f (128 MB)
    float* emis        = xproj + ((size_t)B_ << 20);         // 32*1024*16 f (2 MB)

    prep_kernel<<<128, 256, 0, stream>>>(lengths, seg_off, new_len,
                                         bih_f, bhh_f, bih_b, bhh_b, bias1,
                                         Wih_f, Wih_b, WT1);
    proj_kernel<0><<<dim3(32, 4, B_), 256, 0, stream>>>(texts, emb, WT1, bias1,
                                                        lstm_packed, xproj, seg_off, new_len);
    lstm1_kernel<<<512, 512, 0, stream>>>(lengths, seg_off, Whh_f, Whh_b,
                                          xproj, lstm_packed, hinit, cinit);
    proj_kernel<1><<<dim3(32, 4, B_), 256, 0, stream>>>(texts, emb, WT1, bias1,
                                                        lstm_packed, xproj, seg_off, new_len);
    lstm2_kernel<<<64, 512, 0, stream>>>(new_len, Whh_f, Whh_b,
                                         xproj, lstm_packed, hinit, cinit);
    emission_kernel<<<dim3(64, B_), 256, 0, stream>>>(lstm_packed, Wlin, blin, emis, new_len);
    viterbi_kernel<<<B_, 64, 0, stream>>>(emis, c_start, c_trans, c_end, new_len, out);
}

// Round 8
// 1746.776 us; speedup vs baseline: 1.0412x; 1.0412x over previous
//
#include <hip/hip_runtime.h>
#include <cstdint>
#include <cstddef>

// BiLSTM-CRF forward, MI355X fp32 implementation.
// Pipeline: prep -> proj1(emb gather GEMM) -> lstm1(512 chains) -> proj2(GEMM)
//           -> lstm2(64 chains) -> emission -> viterbi(+backtrace).
// Only valid (packed) tokens are computed; tail tokens provably can't
// affect outputs (mask freezes LSTM2 state and Viterbi score/backtrace).
//
// R8: back to the R4 two-barrier / 2-wave-phase-B structure (R6/R7's
// replicated phase B raised total VALU issue and lost), with the LDS
// redundancy removed: slice-per-wave k-split. Wave w broadcasts-reads ONLY
// its own 16-float h slice (4 b128/wave, 32 instrs/step vs 64), each thread
// computes rows L and L+64 x 4 gates x 16 k. psum[8][128] float4, no parity
// (barrier-protected). KS=4 keeps VGPR ~220 < 256 cap at launch_bounds(512,1)
// so pinned weights can stay in arch VGPRs.

#define B_    32
#define NSEG_ 8
#define S_    128
#define T_    1024
#define E_    256
#define HD_   128
#define G_    512   // 4*HD
#define K_    16
#define KS_   4     // steps per group (global-traffic amortization)

#define PIN4(v) asm volatile("" : "+v"((v).x), "+v"((v).y), "+v"((v).z), "+v"((v).w))

// ---------------- prep: seg offsets, fused bias, transposed+permuted Wih ----------------
// WT1 column jcol (0..1023): dir=jcol>>9, w=jcol&511, j=w>>2, g=w&3 -> gate row r=g*128+j
// so xproj[p][dir*512 + j*4 .. +4] = (i,f,g,o) gates of hidden j (one float4).
__global__ void prep_kernel(const int* __restrict__ lengths,
                            int* __restrict__ seg_off, int* __restrict__ new_len,
                            const float* __restrict__ bih_f, const float* __restrict__ bhh_f,
                            const float* __restrict__ bih_b, const float* __restrict__ bhh_b,
                            float* __restrict__ bias1,
                            const float* __restrict__ Wih_f, const float* __restrict__ Wih_b,
                            float* __restrict__ WT1)
{
    int gtid = blockIdx.x * blockDim.x + threadIdx.x;
    if (gtid < B_) {
        int acc = 0;
        for (int s = 0; s < NSEG_; s++) { seg_off[gtid*NSEG_ + s] = acc; acc += lengths[gtid*NSEG_ + s]; }
        new_len[gtid] = acc;
    }
    if (gtid < 1024) {
        int dir = gtid >> 9, w = gtid & 511, j = w >> 2, g = w & 3;
        int r = g * HD_ + j;
        bias1[gtid] = dir ? (bih_b[r] + bhh_b[r]) : (bih_f[r] + bhh_f[r]);
    }
    for (int e = gtid; e < 256*1024; e += gridDim.x * blockDim.x) {
        int k = e >> 10, jcol = e & 1023;
        int dir = jcol >> 9, w = jcol & 511, j = w >> 2, g = w & 3;
        int r = g * HD_ + j;
        WT1[e] = dir ? Wih_b[(size_t)r*E_ + k] : Wih_f[(size_t)r*E_ + k];
    }
}

// ---------------- projection GEMM: xproj[b][p][j] = A[p][:] . WT1[:][j] + bias1[j] ----------------
// MODE 0: A row = emb_table[texts[...]] (gather); MODE 1: A row = lstm_packed[b][p][:]
template <int MODE>
__global__ void __launch_bounds__(256, 4)
proj_kernel(const int* __restrict__ texts, const float* __restrict__ emb,
            const float* __restrict__ WT1, const float* __restrict__ bias1,
            const float* __restrict__ lstm_packed, float* __restrict__ xproj,
            const int* __restrict__ seg_off, const int* __restrict__ new_len)
{
    int b  = blockIdx.z;
    int nl = new_len[b];
    int p0 = blockIdx.x * 32;
    if (p0 >= nl) return;
    int j0 = blockIdx.y * 256;

    __shared__ __align__(16) float As[32][256];
    __shared__ const float* rowp[32];
    int tid = threadIdx.x;
    if (tid < 32) {
        int p = p0 + tid;
        const float* r = emb;  // dummy row for invalid p
        if (p < nl) {
            if (MODE == 0) {
                int sg = 0;
                #pragma unroll
                for (int q = 1; q < NSEG_; q++) if (seg_off[b*NSEG_ + q] <= p) sg = q;
                int t   = p - seg_off[b*NSEG_ + sg];
                int tok = texts[(b*NSEG_ + sg)*S_ + t];
                r = emb + (size_t)tok * E_;
            } else {
                r = lstm_packed + ((size_t)b*T_ + p) * 256;
            }
        }
        rowp[tid] = r;
    }
    __syncthreads();
    #pragma unroll 4
    for (int i = 0; i < 32; i++) As[i][tid] = rowp[i][tid];
    __syncthreads();

    int pg = tid >> 6;        // 0..3 -> rows pg*8 .. pg*8+7
    int jg = tid & 63;        // cols j0 + jg*4 .. +3
    int j  = j0 + jg*4;
    float acc[8][4];
    #pragma unroll
    for (int i = 0; i < 8; i++) { acc[i][0]=0.f; acc[i][1]=0.f; acc[i][2]=0.f; acc[i][3]=0.f; }

    const float* wbase = WT1 + j;
    for (int k = 0; k < 256; k += 4) {
        float4 w0 = *(const float4*)(wbase + (size_t)(k+0)*1024);
        float4 w1 = *(const float4*)(wbase + (size_t)(k+1)*1024);
        float4 w2 = *(const float4*)(wbase + (size_t)(k+2)*1024);
        float4 w3 = *(const float4*)(wbase + (size_t)(k+3)*1024);
        #pragma unroll
        for (int i = 0; i < 8; i++) {
            float4 a = *(const float4*)&As[pg*8 + i][k];
            acc[i][0] = fmaf(a.w, w3.x, fmaf(a.z, w2.x, fmaf(a.y, w1.x, fmaf(a.x, w0.x, acc[i][0]))));
            acc[i][1] = fmaf(a.w, w3.y, fmaf(a.z, w2.y, fmaf(a.y, w1.y, fmaf(a.x, w0.y, acc[i][1]))));
            acc[i][2] = fmaf(a.w, w3.z, fmaf(a.z, w2.z, fmaf(a.y, w1.z, fmaf(a.x, w0.z, acc[i][2]))));
            acc[i][3] = fmaf(a.w, w3.w, fmaf(a.z, w2.w, fmaf(a.y, w1.w, fmaf(a.x, w0.w, acc[i][3]))));
        }
    }
    float4 bs = *(const float4*)(bias1 + j);
    #pragma unroll
    for (int i = 0; i < 8; i++) {
        int p = p0 + pg*8 + i;
        if (p < nl) {
            float4 r;
            r.x = acc[i][0] + bs.x; r.y = acc[i][1] + bs.y;
            r.z = acc[i][2] + bs.z; r.w = acc[i][3] + bs.w;
            *(float4*)(xproj + (((size_t)b*T_ + p) << 10) + j) = r;
        }
    }
}

// ---------------- LSTM chain v8: two barriers, slice-per-wave ----------------
__device__ __forceinline__ float sig_f(float x) { return 1.0f / (1.0f + __expf(-x)); }
__device__ __forceinline__ float tanh_f(float x) {
    float xc = fminf(fmaxf(x, -15.0f), 15.0f);
    float e  = __expf(-2.0f * xc);
    return (1.0f - e) / (1.0f + e);
}

__device__ __forceinline__ void lstm_chain(
    const float* __restrict__ Whh,     // [512][128] row-major, this dir
    const float* __restrict__ xp,      // xproj for this b: [1024][1024] gate-interleaved
    float* __restrict__ outp,          // lstm_packed for this b: [1024][256]
    int p_base, int len, int dir, int rev,
    const float* __restrict__ h0, const float* __restrict__ c0,
    float* __restrict__ hT, float* __restrict__ cT)
{
    __shared__ __align__(16) float  h_sh[HD_];       // 512 B
    __shared__ __align__(16) float4 psum[8*HD_];     // [slice][row], 16 KB

    int t = threadIdx.x;          // 0..511
    int w = t >> 6, L = t & 63;   // wave, lane
    int ks = 16 * w;              // this wave's k-slice (no cross-wave redundancy)

    // Weights: rows L and L+64, 4 gates (i,f,g,o), k in [ks, ks+16). Pinned.
    float4 wgt[2][4][4];
    #pragma unroll
    for (int rr = 0; rr < 2; rr++) {
        int row = L + 64*rr;
        #pragma unroll
        for (int g = 0; g < 4; g++) {
            const float4* wp = (const float4*)(Whh + (size_t)(g*HD_ + row)*HD_ + ks);
            #pragma unroll
            for (int i = 0; i < 4; i++) { wgt[rr][g][i] = wp[i]; PIN4(wgt[rr][g][i]); }
        }
    }

    float c_reg = 0.0f;
    if (t < HD_) {
        h_sh[t] = h0 ? h0[t] : 0.0f;
        c_reg   = c0 ? c0[t] : 0.0f;
    }
    __syncthreads();

    const float* xb = xp + dir * G_ + 4 * t;   // float4 (i,f,g,o) of row t; t<128
    float*       ob = outp + dir * HD_ + t;    // + p*256

    float4 xc[KS_], xn[KS_];
    float  hbuf[KS_];

    // prefetch group 0 (phase-B threads only)
    if (t < HD_) {
        #pragma unroll
        for (int u = 0; u < KS_; u++) {
            int s = u < len ? u : (len - 1);
            int p = p_base + (rev ? (len - 1 - s) : s);
            xn[u] = *(const float4*)(xb + ((size_t)p << 10));
        }
    }

    for (int gs = 0; gs < len; gs += KS_) {
        // ---- group prologue (2 waves): flush prev hn, rotate, prefetch next ----
        if (t < HD_) {
            if (gs > 0) {
                #pragma unroll
                for (int u = 0; u < KS_; u++) {
                    int s = gs - KS_ + u;
                    int p = p_base + (rev ? (len - 1 - s) : s);
                    ob[(size_t)p * 256] = hbuf[u];
                }
            }
            #pragma unroll
            for (int u = 0; u < KS_; u++) xc[u] = xn[u];
            if (gs + KS_ < len) {
                #pragma unroll
                for (int u = 0; u < KS_; u++) {
                    int s = gs + KS_ + u; s = s < len ? s : (len - 1);
                    int p = p_base + (rev ? (len - 1 - s) : s);
                    xn[u] = *(const float4*)(xb + ((size_t)p << 10));
                }
            }
        }
        // ---- KS_ steps, two barriers each ----
        #pragma unroll
        for (int u = 0; u < KS_; u++) {
            int sstep = gs + u;
            if (sstep < len) {                 // block-uniform predicate
                // matvec over own slice: 4 broadcast b128 reads, 128 FMA
                const float4* hv = (const float4*)(h_sh + ks);
                float4 q0 = make_float4(0.f,0.f,0.f,0.f);
                float4 q1 = q0, q2 = q0, q3 = q0;   // row L: gates i,f,g,o
                float4 Q0 = q0, Q1 = q0, Q2 = q0, Q3 = q0;  // row L+64
                #pragma unroll
                for (int i = 0; i < 4; i++) {
                    float4 h4 = hv[i];
                    q0.x=fmaf(h4.x,wgt[0][0][i].x,q0.x); q0.y=fmaf(h4.y,wgt[0][0][i].y,q0.y);
                    q0.z=fmaf(h4.z,wgt[0][0][i].z,q0.z); q0.w=fmaf(h4.w,wgt[0][0][i].w,q0.w);
                    q1.x=fmaf(h4.x,wgt[0][1][i].x,q1.x); q1.y=fmaf(h4.y,wgt[0][1][i].y,q1.y);
                    q1.z=fmaf(h4.z,wgt[0][1][i].z,q1.z); q1.w=fmaf(h4.w,wgt[0][1][i].w,q1.w);
                    q2.x=fmaf(h4.x,wgt[0][2][i].x,q2.x); q2.y=fmaf(h4.y,wgt[0][2][i].y,q2.y);
                    q2.z=fmaf(h4.z,wgt[0][2][i].z,q2.z); q2.w=fmaf(h4.w,wgt[0][2][i].w,q2.w);
                    q3.x=fmaf(h4.x,wgt[0][3][i].x,q3.x); q3.y=fmaf(h4.y,wgt[0][3][i].y,q3.y);
                    q3.z=fmaf(h4.z,wgt[0][3][i].z,q3.z); q3.w=fmaf(h4.w,wgt[0][3][i].w,q3.w);
                    Q0.x=fmaf(h4.x,wgt[1][0][i].x,Q0.x); Q0.y=fmaf(h4.y,wgt[1][0][i].y,Q0.y);
                    Q0.z=fmaf(h4.z,wgt[1][0][i].z,Q0.z); Q0.w=fmaf(h4.w,wgt[1][0][i].w,Q0.w);
                    Q1.x=fmaf(h4.x,wgt[1][1][i].x,Q1.x); Q1.y=fmaf(h4.y,wgt[1][1][i].y,Q1.y);
                    Q1.z=fmaf(h4.z,wgt[1][1][i].z,Q1.z); Q1.w=fmaf(h4.w,wgt[1][1][i].w,Q1.w);
                    Q2.x=fmaf(h4.x,wgt[1][2][i].x,Q2.x); Q2.y=fmaf(h4.y,wgt[1][2][i].y,Q2.y);
                    Q2.z=fmaf(h4.z,wgt[1][2][i].z,Q2.z); Q2.w=fmaf(h4.w,wgt[1][2][i].w,Q2.w);
                    Q3.x=fmaf(h4.x,wgt[1][3][i].x,Q3.x); Q3.y=fmaf(h4.y,wgt[1][3][i].y,Q3.y);
                    Q3.z=fmaf(h4.z,wgt[1][3][i].z,Q3.z); Q3.w=fmaf(h4.w,wgt[1][3][i].w,Q3.w);
                }
                psum[w*HD_ + L] = make_float4((q0.x+q0.y)+(q0.z+q0.w),
                                              (q1.x+q1.y)+(q1.z+q1.w),
                                              (q2.x+q2.y)+(q2.z+q2.w),
                                              (q3.x+q3.y)+(q3.z+q3.w));
                psum[w*HD_ + L + 64] = make_float4((Q0.x+Q0.y)+(Q0.z+Q0.w),
                                                   (Q1.x+Q1.y)+(Q1.z+Q1.w),
                                                   (Q2.x+Q2.y)+(Q2.z+Q2.w),
                                                   (Q3.x+Q3.y)+(Q3.z+Q3.w));
                __syncthreads();
                if (t < HD_) {                 // phase B: 2 waves, no replication
                    float4 sa = psum[t];
                    #pragma unroll
                    for (int sl = 1; sl < 8; sl++) {
                        float4 p4 = psum[sl*HD_ + t];
                        sa.x += p4.x; sa.y += p4.y; sa.z += p4.z; sa.w += p4.w;
                    }
                    float gi = xc[u].x + sa.x;
                    float gf = xc[u].y + sa.y;
                    float gg = xc[u].z + sa.z;
                    float go = xc[u].w + sa.w;
                    float cn = sig_f(gf) * c_reg + sig_f(gi) * tanh_f(gg);
                    c_reg = cn;
                    float hn = sig_f(go) * tanh_f(cn);
                    h_sh[t] = hn;
                    hbuf[u] = hn;
                    if (sstep == len - 1 && hT != nullptr) { hT[t] = hn; cT[t] = c_reg; }
                }
                __syncthreads();
            }
        }
    }
    // flush last (possibly partial) group
    if (t < HD_ && len > 0) {
        int gs0 = ((len - 1) / KS_) * KS_;
        #pragma unroll
        for (int u = 0; u < KS_; u++) {
            int s = gs0 + u;
            if (s < len) {
                int p = p_base + (rev ? (len - 1 - s) : s);
                ob[(size_t)p * 256] = hbuf[u];
            }
        }
    }
}

__global__ void __launch_bounds__(512, 1)
lstm1_kernel(const int* __restrict__ lengths, const int* __restrict__ seg_off,
             const float* __restrict__ Whh_f, const float* __restrict__ Whh_b,
             const float* __restrict__ xproj, float* __restrict__ lstm_packed,
             float* __restrict__ hinit, float* __restrict__ cinit)
{
    int cid = blockIdx.x;                 // 512 = 32b * 8seg * 2dir
    int b = cid >> 4, seg = (cid >> 1) & 7, dir = cid & 1;
    int len = lengths[b*NSEG_ + seg];
    int pb  = seg_off[b*NSEG_ + seg];
    const float* Whh = dir ? Whh_b : Whh_f;
    float* hT = nullptr; float* cT = nullptr;
    if (seg == NSEG_ - 1) {               // final states feed LSTM2 init
        hT = hinit + (dir*B_ + b)*HD_;
        cT = cinit + (dir*B_ + b)*HD_;
    }
    lstm_chain(Whh, xproj + ((size_t)b << 20), lstm_packed + (size_t)b*T_*256,
               pb, len, dir, dir, nullptr, nullptr, hT, cT);
}

__global__ void __launch_bounds__(512, 1)
lstm2_kernel(const int* __restrict__ new_len,
             const float* __restrict__ Whh_f, const float* __restrict__ Whh_b,
             const float* __restrict__ xproj, float* __restrict__ lstm_packed,
             const float* __restrict__ hinit, const float* __restrict__ cinit)
{
    int cid = blockIdx.x;                 // 64 = 32b * 2dir
    int b = cid >> 1, dir = cid & 1;
    int len = new_len[b];
    const float* Whh = dir ? Whh_b : Whh_f;
    lstm_chain(Whh, xproj + ((size_t)b << 20), lstm_packed + (size_t)b*T_*256,
               0, len, dir, dir,
               hinit + (dir*B_ + b)*HD_, cinit + (dir*B_ + b)*HD_,
               nullptr, nullptr);
}

// ---------------- emission: em[b][p][s] = lstm2[b][p][:] . Wlin[s][:] + blin[s] ----------------
__global__ void __launch_bounds__(256)
emission_kernel(const float* __restrict__ lstm_packed, const float* __restrict__ Wlin,
                const float* __restrict__ blin, float* __restrict__ emis,
                const int* __restrict__ new_len)
{
    int b  = blockIdx.y;
    int nl = new_len[b];
    int p0 = blockIdx.x * 16;
    if (p0 >= nl) return;
    int pl = threadIdx.x >> 4, s = threadIdx.x & 15;
    int p  = p0 + pl;
    const float4* xr = (const float4*)(lstm_packed + ((size_t)b*T_ + p) * 256);
    const float4* wr = (const float4*)(Wlin + (size_t)s * 256);
    float ax = 0.f, ay = 0.f, az = 0.f, aw = 0.f;
    #pragma unroll
    for (int i = 0; i < 64; i++) {
        float4 a = xr[i]; float4 ww = wr[i];
        ax = fmaf(a.x, ww.x, ax); ay = fmaf(a.y, ww.y, ay);
        az = fmaf(a.z, ww.z, az); aw = fmaf(a.w, ww.w, aw);
    }
    if (p < nl) emis[((size_t)b*T_ + p)*K_ + s] = (ax + ay) + (az + aw) + blin[s];
}

// ---------------- Viterbi: one block (1 wave) per batch element ----------------
__global__ void __launch_bounds__(64)
viterbi_kernel(const float* __restrict__ emis, const float* __restrict__ start,
               const float* __restrict__ trans, const float* __restrict__ endv,
               const int* __restrict__ new_len, float* __restrict__ out)
{
    int b    = blockIdx.x;
    int nl   = new_len[b];
    int lane = threadIdx.x;          // 64 lanes: 4 q-groups x 16 states
    int s    = lane & 15, q4 = lane >> 4;

    __shared__ unsigned char hist[T_ * K_];   // 16 KB
    __shared__ unsigned char tagb[T_];

    float tr[4];
    #pragma unroll
    for (int jj = 0; jj < 4; jj++) tr[jj] = trans[(q4*4 + jj)*K_ + s];

    const float* em = emis + (size_t)b * T_ * K_;
    float sc = start[s] + em[s];     // p = 0 (always valid)

    for (int p = 1; p < nl; p++) {
        float e = em[p*K_ + s];
        float m = -3.4e38f; int a = 0;
        #pragma unroll
        for (int jj = 0; jj < 4; jj++) {
            int q   = q4*4 + jj;
            float sq = __shfl(sc, q, 16);
            float v  = sq + tr[jj];
            if (v > m) { m = v; a = q; }
        }
        #pragma unroll
        for (int d = 16; d < 64; d <<= 1) {
            float mo = __shfl_xor(m, d);
            int   ao = __shfl_xor(a, d);
            if (mo > m || (mo == m && ao < a)) { m = mo; a = ao; }
        }
        sc = m + e;
        if (lane < K_) hist[p*K_ + s] = (unsigned char)a;
    }

    // final = sc + end; best/argmax (first index on ties)
    float m = sc + endv[s]; int a = s;
    #pragma unroll
    for (int d = 1; d < 16; d <<= 1) {
        float mo = __shfl_xor(m, d);
        int   ao = __shfl_xor(a, d);
        if (mo > m || (mo == m && ao < a)) { m = mo; a = ao; }
    }
    int last = a;
    if (lane == 0) out[T_*B_ + b] = m;
    __syncthreads();

    for (int i = lane; i < T_; i += 64) tagb[i] = (unsigned char)last;
    __syncthreads();
    if (lane == 0) {
        int cur = last;
        for (int j = nl - 2; j >= 0; j--) {
            cur = hist[(j+1)*K_ + cur];
            tagb[j] = (unsigned char)cur;
        }
    }
    __syncthreads();
    for (int i = lane; i < T_; i += 64) out[(size_t)i*B_ + b] = (float)tagb[i];
}

// ---------------- host ----------------
extern "C" void kernel_launch(void* const* d_in, const int* in_sizes, int n_in,
                              void* d_out, int out_size, void* d_ws, size_t ws_size,
                              hipStream_t stream)
{
    (void)in_sizes; (void)n_in; (void)out_size; (void)ws_size;
    const int*   texts   = (const int*)  d_in[0];
    const int*   lengths = (const int*)  d_in[1];
    const float* emb     = (const float*)d_in[2];
    const float* Wih_f   = (const float*)d_in[3];
    const float* Whh_f   = (const float*)d_in[4];
    const float* bih_f   = (const float*)d_in[5];
    const float* bhh_f   = (const float*)d_in[6];
    const float* Wih_b   = (const float*)d_in[7];
    const float* Whh_b   = (const float*)d_in[8];
    const float* bih_b   = (const float*)d_in[9];
    const float* bhh_b   = (const float*)d_in[10];
    const float* Wlin    = (const float*)d_in[11];
    const float* blin    = (const float*)d_in[12];
    const float* c_start = (const float*)d_in[13];
    const float* c_trans = (const float*)d_in[14];
    const float* c_end   = (const float*)d_in[15];
    float* out = (float*)d_out;

    // workspace carve (~163 MB total, all 16B-aligned)
    char* w = (char*)d_ws;
    int*   seg_off     = (int*)(w);                      // 256 ints
    int*   new_len     = (int*)(w + 1024);               // 32 ints
    float* bias1       = (float*)(w + 4096);             // 1024 f
    float* WT1         = (float*)(w + 8192);             // 262144 f (1 MB)
    float* hinit       = (float*)(w + 8192 + 1048576);   // 8192 f
    float* cinit       = hinit + 8192;                   // 8192 f
    float* lstm_packed = cinit + 8192;                   // 32*1024*256 f (32 MB)
    float* xproj       = lstm_packed + (size_t)B_*T_*256;    // 32*1024*1024 f (128 MB)
    float* emis        = xproj + ((size_t)B_ << 20);         // 32*1024*16 f (2 MB)

    prep_kernel<<<128, 256, 0, stream>>>(lengths, seg_off, new_len,
                                         bih_f, bhh_f, bih_b, bhh_b, bias1,
                                         Wih_f, Wih_b, WT1);
    proj_kernel<0><<<dim3(32, 4, B_), 256, 0, stream>>>(texts, emb, WT1, bias1,
                                                        lstm_packed, xproj, seg_off, new_len);
    lstm1_kernel<<<512, 512, 0, stream>>>(lengths, seg_off, Whh_f, Whh_b,
                                          xproj, lstm_packed, hinit, cinit);
    proj_kernel<1><<<dim3(32, 4, B_), 256, 0, stream>>>(texts, emb, WT1, bias1,
                                                        lstm_packed, xproj, seg_off, new_len);
    lstm2_kernel<<<64, 512, 0, stream>>>(new_len, Whh_f, Whh_b,
                                         xproj, lstm_packed, hinit, cinit);
    emission_kernel<<<dim3(64, B_), 256, 0, stream>>>(lstm_packed, Wlin, blin, emis, new_len);
    viterbi_kernel<<<B_, 64, 0, stream>>>(emis, c_start, c_trans, c_end, new_len, out);
}

// Round 9
// 1658.499 us; speedup vs baseline: 1.0966x; 1.0532x over previous
//
#include <hip/hip_runtime.h>
#include <cstdint>
#include <cstddef>

// BiLSTM-CRF forward, MI355X fp32 implementation.
// Pipeline: prep -> proj1(emb gather GEMM) -> lstm1(512 chains) -> proj2(GEMM)
//           -> lstm2(64 chains) -> emission -> viterbi(+backtrace).
// Only valid (packed) tokens are computed; tail tokens provably can't
// affect outputs (mask freezes LSTM2 state and Viterbi score/backtrace).
//
// R9: shfl-reduced LSTM step. Thread = (row r=16w+(L&15), k-quarter kq=L>>4):
// 128 FMA/thread as before, but the k-reduction happens IN-WAVE via
// __shfl_xor(16/32) gate-split butterfly (no psum LDS roundtrip, no 2-wave
// phase-B serialization - each wave finalizes its own 16 rows). One barrier
// per step; h parity-double-buffered (2x512B LDS). h matvec reads are
// broadcast ds_read_b128 with kq-rotation so the 4 kq groups hit disjoint
// banks. Gates: branchless single-exp sigmoid/tanh + v_rcp+NR.

#define B_    32
#define NSEG_ 8
#define S_    128
#define T_    1024
#define E_    256
#define HD_   128
#define G_    512   // 4*HD
#define K_    16
#define KS_   8     // steps per group (global-traffic amortization)

#define PIN4(v) asm volatile("" : "+v"((v).x), "+v"((v).y), "+v"((v).z), "+v"((v).w))

__device__ __forceinline__ float fast_rcp(float x) {
    float r;
    asm("v_rcp_f32 %0, %1" : "=v"(r) : "v"(x));
    r = r * (2.0f - x * r);          // one Newton step -> ~fp32 accurate
    return r;
}

// ---------------- prep: seg offsets, fused bias, transposed+permuted Wih ----------------
// WT1 column jcol (0..1023): dir=jcol>>9, w=jcol&511, j=w>>2, g=w&3 -> gate row r=g*128+j
// so xproj[p][dir*512 + j*4 .. +4] = (i,f,g,o) gates of hidden j (one float4).
__global__ void prep_kernel(const int* __restrict__ lengths,
                            int* __restrict__ seg_off, int* __restrict__ new_len,
                            const float* __restrict__ bih_f, const float* __restrict__ bhh_f,
                            const float* __restrict__ bih_b, const float* __restrict__ bhh_b,
                            float* __restrict__ bias1,
                            const float* __restrict__ Wih_f, const float* __restrict__ Wih_b,
                            float* __restrict__ WT1)
{
    int gtid = blockIdx.x * blockDim.x + threadIdx.x;
    if (gtid < B_) {
        int acc = 0;
        for (int s = 0; s < NSEG_; s++) { seg_off[gtid*NSEG_ + s] = acc; acc += lengths[gtid*NSEG_ + s]; }
        new_len[gtid] = acc;
    }
    if (gtid < 1024) {
        int dir = gtid >> 9, w = gtid & 511, j = w >> 2, g = w & 3;
        int r = g * HD_ + j;
        bias1[gtid] = dir ? (bih_b[r] + bhh_b[r]) : (bih_f[r] + bhh_f[r]);
    }
    for (int e = gtid; e < 256*1024; e += gridDim.x * blockDim.x) {
        int k = e >> 10, jcol = e & 1023;
        int dir = jcol >> 9, w = jcol & 511, j = w >> 2, g = w & 3;
        int r = g * HD_ + j;
        WT1[e] = dir ? Wih_b[(size_t)r*E_ + k] : Wih_f[(size_t)r*E_ + k];
    }
}

// ---------------- projection GEMM: xproj[b][p][j] = A[p][:] . WT1[:][j] + bias1[j] ----------------
// MODE 0: A row = emb_table[texts[...]] (gather); MODE 1: A row = lstm_packed[b][p][:]
template <int MODE>
__global__ void __launch_bounds__(256, 4)
proj_kernel(const int* __restrict__ texts, const float* __restrict__ emb,
            const float* __restrict__ WT1, const float* __restrict__ bias1,
            const float* __restrict__ lstm_packed, float* __restrict__ xproj,
            const int* __restrict__ seg_off, const int* __restrict__ new_len)
{
    int b  = blockIdx.z;
    int nl = new_len[b];
    int p0 = blockIdx.x * 32;
    if (p0 >= nl) return;
    int j0 = blockIdx.y * 256;

    __shared__ __align__(16) float As[32][256];
    __shared__ const float* rowp[32];
    int tid = threadIdx.x;
    if (tid < 32) {
        int p = p0 + tid;
        const float* r = emb;  // dummy row for invalid p
        if (p < nl) {
            if (MODE == 0) {
                int sg = 0;
                #pragma unroll
                for (int q = 1; q < NSEG_; q++) if (seg_off[b*NSEG_ + q] <= p) sg = q;
                int t   = p - seg_off[b*NSEG_ + sg];
                int tok = texts[(b*NSEG_ + sg)*S_ + t];
                r = emb + (size_t)tok * E_;
            } else {
                r = lstm_packed + ((size_t)b*T_ + p) * 256;
            }
        }
        rowp[tid] = r;
    }
    __syncthreads();
    #pragma unroll 4
    for (int i = 0; i < 32; i++) As[i][tid] = rowp[i][tid];
    __syncthreads();

    int pg = tid >> 6;        // 0..3 -> rows pg*8 .. pg*8+7
    int jg = tid & 63;        // cols j0 + jg*4 .. +3
    int j  = j0 + jg*4;
    float acc[8][4];
    #pragma unroll
    for (int i = 0; i < 8; i++) { acc[i][0]=0.f; acc[i][1]=0.f; acc[i][2]=0.f; acc[i][3]=0.f; }

    const float* wbase = WT1 + j;
    for (int k = 0; k < 256; k += 4) {
        float4 w0 = *(const float4*)(wbase + (size_t)(k+0)*1024);
        float4 w1 = *(const float4*)(wbase + (size_t)(k+1)*1024);
        float4 w2 = *(const float4*)(wbase + (size_t)(k+2)*1024);
        float4 w3 = *(const float4*)(wbase + (size_t)(k+3)*1024);
        #pragma unroll
        for (int i = 0; i < 8; i++) {
            float4 a = *(const float4*)&As[pg*8 + i][k];
            acc[i][0] = fmaf(a.w, w3.x, fmaf(a.z, w2.x, fmaf(a.y, w1.x, fmaf(a.x, w0.x, acc[i][0]))));
            acc[i][1] = fmaf(a.w, w3.y, fmaf(a.z, w2.y, fmaf(a.y, w1.y, fmaf(a.x, w0.y, acc[i][1]))));
            acc[i][2] = fmaf(a.w, w3.z, fmaf(a.z, w2.z, fmaf(a.y, w1.z, fmaf(a.x, w0.z, acc[i][2]))));
            acc[i][3] = fmaf(a.w, w3.w, fmaf(a.z, w2.w, fmaf(a.y, w1.w, fmaf(a.x, w0.w, acc[i][3]))));
        }
    }
    float4 bs = *(const float4*)(bias1 + j);
    #pragma unroll
    for (int i = 0; i < 8; i++) {
        int p = p0 + pg*8 + i;
        if (p < nl) {
            float4 r;
            r.x = acc[i][0] + bs.x; r.y = acc[i][1] + bs.y;
            r.z = acc[i][2] + bs.z; r.w = acc[i][3] + bs.w;
            *(float4*)(xproj + (((size_t)b*T_ + p) << 10) + j) = r;
        }
    }
}

// ---------------- LSTM chain v9: shfl-reduced, one barrier ----------------
__device__ __forceinline__ void lstm_chain(
    const float* __restrict__ Whh,     // [512][128] row-major, this dir
    const float* __restrict__ xp,      // xproj for this b: [1024][1024] gate-interleaved
    float* __restrict__ outp,          // lstm_packed for this b: [1024][256]
    int p_base, int len, int dir, int rev,
    const float* __restrict__ h0, const float* __restrict__ c0,
    float* __restrict__ hT, float* __restrict__ cT)
{
    __shared__ __align__(16) float h_sh[2*HD_];    // parity double buffer, 1 KB

    int t  = threadIdx.x;           // 0..511
    int w  = t >> 6, L = t & 63;    // wave, lane
    int kq = L >> 4;                // k-quarter: [32kq, 32kq+32)
    int rl = L & 15;
    int r  = 16*w + rl;             // row handled by lanes {rl, rl+16, rl+32, rl+48}
    int odd = kq & 1;
    int rot = 2 * kq;               // bank-stagger rotation

    // Weights: 4 gates x 32 k of row r, loaded rotated so FMA iter i uses
    // h-chunk ((rot+i)&7) -> kq groups hit disjoint banks. 128 VGPRs, pinned.
    float4 wgt[4][8];
    #pragma unroll
    for (int g = 0; g < 4; g++) {
        const float4* wp = (const float4*)(Whh + (size_t)(g*HD_ + r)*HD_ + 32*kq);
        #pragma unroll
        for (int i = 0; i < 8; i++) { wgt[g][i] = wp[(rot + i) & 7]; PIN4(wgt[g][i]); }
    }

    float c_reg = 0.0f;
    if (!odd) c_reg = c0 ? c0[r] : 0.0f;       // kq0 & kq2 both carry c
    if (L < 16) h_sh[r] = h0 ? h0[r] : 0.0f;   // buffer 0
    __syncthreads();

    const float* xb = xp + dir * G_ + 4*r + 2*odd;   // float2 of this lane's gate pair
    float*       ob = outp + dir * HD_ + r;          // storer lanes (L<16)

    float2 xc[KS_], xn[KS_];
    float  hbuf[KS_];

    // prefetch group 0
    #pragma unroll
    for (int u = 0; u < KS_; u++) {
        int s = u < len ? u : (len - 1);
        int p = p_base + (rev ? (len - 1 - s) : s);
        xn[u] = *(const float2*)(xb + ((size_t)p << 10));
    }

    for (int gs = 0; gs < len; gs += KS_) {
        // ---- group prologue: flush prev hn (storer lanes), rotate, prefetch ----
        if (L < 16 && gs > 0) {
            #pragma unroll
            for (int u = 0; u < KS_; u++) {
                int s = gs - KS_ + u;
                int p = p_base + (rev ? (len - 1 - s) : s);
                ob[(size_t)p * 256] = hbuf[u];
            }
        }
        #pragma unroll
        for (int u = 0; u < KS_; u++) xc[u] = xn[u];
        if (gs + KS_ < len) {
            #pragma unroll
            for (int u = 0; u < KS_; u++) {
                int s = gs + KS_ + u; s = s < len ? s : (len - 1);
                int p = p_base + (rev ? (len - 1 - s) : s);
                xn[u] = *(const float2*)(xb + ((size_t)p << 10));
            }
        }
        // ---- KS_ steps, ONE barrier each ----
        #pragma unroll
        for (int u = 0; u < KS_; u++) {
            int sstep = gs + u;
            if (sstep < len) {                 // block-uniform predicate
                int par = (sstep & 1) * HD_;
                const float* hb = h_sh + par + 32*kq;
                // matvec: 4 gates x 32 k, rotated broadcast b128 reads
                float4 a0 = make_float4(0.f,0.f,0.f,0.f);
                float4 a1 = a0, a2 = a0, a3 = a0;
                #pragma unroll
                for (int i = 0; i < 8; i++) {
                    float4 h4 = *(const float4*)(hb + 4*((rot + i) & 7));
                    a0.x=fmaf(h4.x,wgt[0][i].x,a0.x); a0.y=fmaf(h4.y,wgt[0][i].y,a0.y);
                    a0.z=fmaf(h4.z,wgt[0][i].z,a0.z); a0.w=fmaf(h4.w,wgt[0][i].w,a0.w);
                    a1.x=fmaf(h4.x,wgt[1][i].x,a1.x); a1.y=fmaf(h4.y,wgt[1][i].y,a1.y);
                    a1.z=fmaf(h4.z,wgt[1][i].z,a1.z); a1.w=fmaf(h4.w,wgt[1][i].w,a1.w);
                    a2.x=fmaf(h4.x,wgt[2][i].x,a2.x); a2.y=fmaf(h4.y,wgt[2][i].y,a2.y);
                    a2.z=fmaf(h4.z,wgt[2][i].z,a2.z); a2.w=fmaf(h4.w,wgt[2][i].w,a2.w);
                    a3.x=fmaf(h4.x,wgt[3][i].x,a3.x); a3.y=fmaf(h4.y,wgt[3][i].y,a3.y);
                    a3.z=fmaf(h4.z,wgt[3][i].z,a3.z); a3.w=fmaf(h4.w,wgt[3][i].w,a3.w);
                }
                float p0 = (a0.x+a0.y)+(a0.z+a0.w);   // gate i partial (this kq)
                float p1 = (a1.x+a1.y)+(a1.z+a1.w);   // f
                float p2 = (a2.x+a2.y)+(a2.z+a2.w);   // g
                float p3 = (a3.x+a3.y)+(a3.z+a3.w);   // o
                // gate-split butterfly: xor16 halves gates, xor32 completes k
                float sx = __shfl_xor(odd ? p0 : p2, 16);
                float sy = __shfl_xor(odd ? p1 : p3, 16);
                float qa = (odd ? p2 : p0) + sx;      // even: i   odd: g
                float qb = (odd ? p3 : p1) + sy;      // even: f   odd: o
                qa += __shfl_xor(qa, 32);
                qb += __shfl_xor(qb, 32);
                qa += xc[u].x;
                qb += xc[u].y;
                // nonlinearity: even->sig(qa), odd->tanh(qa); qb always sig
                float qc  = fminf(fmaxf(qa, -15.0f), 15.0f);
                float e1  = __expf(odd ? -2.0f*qc : -qa);
                float num = odd ? (1.0f - e1) : 1.0f;
                float ah  = num * fast_rcp(1.0f + e1);   // even: î   odd: tanh(g)
                float bh  = fast_rcp(1.0f + __expf(-qb));// even: f̂   odd: ô
                float gh  = __shfl_xor(ah, 16);          // even lanes: tanh(g)
                float oh  = __shfl_xor(bh, 16);          // even lanes: ô
                float cn  = bh * c_reg + ah * gh;        // meaningful at even lanes
                c_reg = cn;
                float cc  = fminf(fmaxf(cn, -15.0f), 15.0f);
                float e3  = __expf(-2.0f * cc);
                float th  = (1.0f - e3) * fast_rcp(1.0f + e3);
                float hn  = oh * th;
                if (L < 16) h_sh[(par ^ HD_) + r] = hn;  // next parity buffer
                hbuf[u] = hn;
                if (sstep == len - 1 && hT != nullptr && L < 16) {
                    hT[r] = hn; cT[r] = c_reg;
                }
                __syncthreads();
            }
        }
    }
    // flush last (possibly partial) group
    if (L < 16 && len > 0) {
        int gs0 = ((len - 1) / KS_) * KS_;
        #pragma unroll
        for (int u = 0; u < KS_; u++) {
            int s = gs0 + u;
            if (s < len) {
                int p = p_base + (rev ? (len - 1 - s) : s);
                ob[(size_t)p * 256] = hbuf[u];
            }
        }
    }
}

__global__ void __launch_bounds__(512, 1)
lstm1_kernel(const int* __restrict__ lengths, const int* __restrict__ seg_off,
             const float* __restrict__ Whh_f, const float* __restrict__ Whh_b,
             const float* __restrict__ xproj, float* __restrict__ lstm_packed,
             float* __restrict__ hinit, float* __restrict__ cinit)
{
    int cid = blockIdx.x;                 // 512 = 32b * 8seg * 2dir
    int b = cid >> 4, seg = (cid >> 1) & 7, dir = cid & 1;
    int len = lengths[b*NSEG_ + seg];
    int pb  = seg_off[b*NSEG_ + seg];
    const float* Whh = dir ? Whh_b : Whh_f;
    float* hT = nullptr; float* cT = nullptr;
    if (seg == NSEG_ - 1) {               // final states feed LSTM2 init
        hT = hinit + (dir*B_ + b)*HD_;
        cT = cinit + (dir*B_ + b)*HD_;
    }
    lstm_chain(Whh, xproj + ((size_t)b << 20), lstm_packed + (size_t)b*T_*256,
               pb, len, dir, dir, nullptr, nullptr, hT, cT);
}

__global__ void __launch_bounds__(512, 1)
lstm2_kernel(const int* __restrict__ new_len,
             const float* __restrict__ Whh_f, const float* __restrict__ Whh_b,
             const float* __restrict__ xproj, float* __restrict__ lstm_packed,
             const float* __restrict__ hinit, const float* __restrict__ cinit)
{
    int cid = blockIdx.x;                 // 64 = 32b * 2dir
    int b = cid >> 1, dir = cid & 1;
    int len = new_len[b];
    const float* Whh = dir ? Whh_b : Whh_f;
    lstm_chain(Whh, xproj + ((size_t)b << 20), lstm_packed + (size_t)b*T_*256,
               0, len, dir, dir,
               hinit + (dir*B_ + b)*HD_, cinit + (dir*B_ + b)*HD_,
               nullptr, nullptr);
}

// ---------------- emission: em[b][p][s] = lstm2[b][p][:] . Wlin[s][:] + blin[s] ----------------
__global__ void __launch_bounds__(256)
emission_kernel(const float* __restrict__ lstm_packed, const float* __restrict__ Wlin,
                const float* __restrict__ blin, float* __restrict__ emis,
                const int* __restrict__ new_len)
{
    int b  = blockIdx.y;
    int nl = new_len[b];
    int p0 = blockIdx.x * 16;
    if (p0 >= nl) return;
    int pl = threadIdx.x >> 4, s = threadIdx.x & 15;
    int p  = p0 + pl;
    const float4* xr = (const float4*)(lstm_packed + ((size_t)b*T_ + p) * 256);
    const float4* wr = (const float4*)(Wlin + (size_t)s * 256);
    float ax = 0.f, ay = 0.f, az = 0.f, aw = 0.f;
    #pragma unroll
    for (int i = 0; i < 64; i++) {
        float4 a = xr[i]; float4 ww = wr[i];
        ax = fmaf(a.x, ww.x, ax); ay = fmaf(a.y, ww.y, ay);
        az = fmaf(a.z, ww.z, az); aw = fmaf(a.w, ww.w, aw);
    }
    if (p < nl) emis[((size_t)b*T_ + p)*K_ + s] = (ax + ay) + (az + aw) + blin[s];
}

// ---------------- Viterbi: one block (1 wave) per batch element ----------------
__global__ void __launch_bounds__(64)
viterbi_kernel(const float* __restrict__ emis, const float* __restrict__ start,
               const float* __restrict__ trans, const float* __restrict__ endv,
               const int* __restrict__ new_len, float* __restrict__ out)
{
    int b    = blockIdx.x;
    int nl   = new_len[b];
    int lane = threadIdx.x;          // 64 lanes: 4 q-groups x 16 states
    int s    = lane & 15, q4 = lane >> 4;

    __shared__ unsigned char hist[T_ * K_];   // 16 KB
    __shared__ unsigned char tagb[T_];

    float tr[4];
    #pragma unroll
    for (int jj = 0; jj < 4; jj++) tr[jj] = trans[(q4*4 + jj)*K_ + s];

    const float* em = emis + (size_t)b * T_ * K_;
    float sc = start[s] + em[s];     // p = 0 (always valid)

    for (int p = 1; p < nl; p++) {
        float e = em[p*K_ + s];
        float m = -3.4e38f; int a = 0;
        #pragma unroll
        for (int jj = 0; jj < 4; jj++) {
            int q   = q4*4 + jj;
            float sq = __shfl(sc, q, 16);
            float v  = sq + tr[jj];
            if (v > m) { m = v; a = q; }
        }
        #pragma unroll
        for (int d = 16; d < 64; d <<= 1) {
            float mo = __shfl_xor(m, d);
            int   ao = __shfl_xor(a, d);
            if (mo > m || (mo == m && ao < a)) { m = mo; a = ao; }
        }
        sc = m + e;
        if (lane < K_) hist[p*K_ + s] = (unsigned char)a;
    }

    // final = sc + end; best/argmax (first index on ties)
    float m = sc + endv[s]; int a = s;
    #pragma unroll
    for (int d = 1; d < 16; d <<= 1) {
        float mo = __shfl_xor(m, d);
        int   ao = __shfl_xor(a, d);
        if (mo > m || (mo == m && ao < a)) { m = mo; a = ao; }
    }
    int last = a;
    if (lane == 0) out[T_*B_ + b] = m;
    __syncthreads();

    for (int i = lane; i < T_; i += 64) tagb[i] = (unsigned char)last;
    __syncthreads();
    if (lane == 0) {
        int cur = last;
        for (int j = nl - 2; j >= 0; j--) {
            cur = hist[(j+1)*K_ + cur];
            tagb[j] = (unsigned char)cur;
        }
    }
    __syncthreads();
    for (int i = lane; i < T_; i += 64) out[(size_t)i*B_ + b] = (float)tagb[i];
}

// ---------------- host ----------------
extern "C" void kernel_launch(void* const* d_in, const int* in_sizes, int n_in,
                              void* d_out, int out_size, void* d_ws, size_t ws_size,
                              hipStream_t stream)
{
    (void)in_sizes; (void)n_in; (void)out_size; (void)ws_size;
    const int*   texts   = (const int*)  d_in[0];
    const int*   lengths = (const int*)  d_in[1];
    const float* emb     = (const float*)d_in[2];
    const float* Wih_f   = (const float*)d_in[3];
    const float* Whh_f   = (const float*)d_in[4];
    const float* bih_f   = (const float*)d_in[5];
    const float* bhh_f   = (const float*)d_in[6];
    const float* Wih_b   = (const float*)d_in[7];
    const float* Whh_b   = (const float*)d_in[8];
    const float* bih_b   = (const float*)d_in[9];
    const float* bhh_b   = (const float*)d_in[10];
    const float* Wlin    = (const float*)d_in[11];
    const float* blin    = (const float*)d_in[12];
    const float* c_start = (const float*)d_in[13];
    const float* c_trans = (const float*)d_in[14];
    const float* c_end   = (const float*)d_in[15];
    float* out = (float*)d_out;

    // workspace carve (~163 MB total, all 16B-aligned)
    char* w = (char*)d_ws;
    int*   seg_off     = (int*)(w);                      // 256 ints
    int*   new_len     = (int*)(w + 1024);               // 32 ints
    float* bias1       = (float*)(w + 4096);             // 1024 f
    float* WT1         = (float*)(w + 8192);             // 262144 f (1 MB)
    float* hinit       = (float*)(w + 8192 + 1048576);   // 8192 f
    float* cinit       = hinit + 8192;                   // 8192 f
    float* lstm_packed = cinit + 8192;                   // 32*1024*256 f (32 MB)
    float* xproj       = lstm_packed + (size_t)B_*T_*256;    // 32*1024*1024 f (128 MB)
    float* emis        = xproj + ((size_t)B_ << 20);         // 32*1024*16 f (2 MB)

    prep_kernel<<<128, 256, 0, stream>>>(lengths, seg_off, new_len,
                                         bih_f, bhh_f, bih_b, bhh_b, bias1,
                                         Wih_f, Wih_b, WT1);
    proj_kernel<0><<<dim3(32, 4, B_), 256, 0, stream>>>(texts, emb, WT1, bias1,
                                                        lstm_packed, xproj, seg_off, new_len);
    lstm1_kernel<<<512, 512, 0, stream>>>(lengths, seg_off, Whh_f, Whh_b,
                                          xproj, lstm_packed, hinit, cinit);
    proj_kernel<1><<<dim3(32, 4, B_), 256, 0, stream>>>(texts, emb, WT1, bias1,
                                                        lstm_packed, xproj, seg_off, new_len);
    lstm2_kernel<<<64, 512, 0, stream>>>(new_len, Whh_f, Whh_b,
                                         xproj, lstm_packed, hinit, cinit);
    emission_kernel<<<dim3(64, B_), 256, 0, stream>>>(lstm_packed, Wlin, blin, emis, new_len);
    viterbi_kernel<<<B_, 64, 0, stream>>>(emis, c_start, c_trans, c_end, new_len, out);
}